// Round 1
// baseline (1071.038 us; speedup 1.0000x reference)
//
#include <hip/hip_runtime.h>
#include <hip/hip_bf16.h>
#include <stdint.h>

// Problem constants
#define M_ROWS   32768            // 4*8192
#define K_DIM    1024             // D_MODEL
#define N_COLS   4112             // TOTAL
#define N_PAD    4224             // 33*128 (W padded with zero rows)
#define SEC_ELEMS 33554432ull     // 32768*1024, one output section

typedef __bf16  bf16x8 __attribute__((ext_vector_type(8)));
typedef float   f32x4  __attribute__((ext_vector_type(4)));

__device__ __forceinline__ unsigned short f2bf(float f) {
    // round-to-nearest-even fp32 -> bf16
    uint32_t u = __float_as_uint(f);
    u += 0x7fffu + ((u >> 16) & 1u);
    return (unsigned short)(u >> 16);
}

// ---- conversion kernels -------------------------------------------------
__global__ void cvt_x_kernel(const float* __restrict__ x, unsigned short* __restrict__ xb) {
    int i = blockIdx.x * 256 + threadIdx.x;   // exactly 8388608 threads, no bounds needed
    float4 v = ((const float4*)x)[i];
    ushort4 o;
    o.x = f2bf(v.x); o.y = f2bf(v.y); o.z = f2bf(v.z); o.w = f2bf(v.w);
    ((ushort4*)xb)[i] = o;
}

__global__ void cvt_w_kernel(const float* __restrict__ W, unsigned short* __restrict__ Wb) {
    int i = blockIdx.x * 256 + threadIdx.x;   // covers N_PAD*K_DIM/4 = 1081344
    ushort4 o;
    if (i < (N_COLS * K_DIM / 4)) {           // 1052672 valid float4s
        float4 v = ((const float4*)W)[i];
        o.x = f2bf(v.x); o.y = f2bf(v.y); o.z = f2bf(v.z); o.w = f2bf(v.w);
    } else {
        o.x = 0; o.y = 0; o.z = 0; o.w = 0;   // zero-pad rows 4112..4223
    }
    ((ushort4*)Wb)[i] = o;
}

// ---- main GEMM (m97 structure: 128x128 tile, global_load_lds w=16) ------
#define GLOAD_LDS16(gp, lp)                                                  \
    __builtin_amdgcn_global_load_lds(                                        \
        (const __attribute__((address_space(1))) void*)(gp),                 \
        (__attribute__((address_space(3))) void*)(lp), 16, 0, 0)

__global__ __launch_bounds__(256) void gemm_kernel(
        const unsigned short* __restrict__ A,   // M_ROWS x 1024 bf16
        const unsigned short* __restrict__ B,   // N_PAD  x 1024 bf16 (row = out col)
        float* __restrict__ out) {
    __shared__ unsigned short sA[128 * 32];
    __shared__ unsigned short sB[128 * 32];

    const int t  = threadIdx.x;
    const int w  = t >> 6;       // wave 0..3
    const int l  = t & 63;       // lane
    const int bx = blockIdx.x;   // col tile 0..32
    const int by = blockIdx.y;   // row tile 0..255

    // staging: each wave fills two 16-row segments of each tile (16B/lane)
    const int s0 = 2 * w, s1 = 2 * w + 1;
    const int lr = l >> 2;            // row within segment
    const int lk = (l & 3) * 8;       // k offset (8 bf16 = 16B)
    const unsigned short* a0 = A + (size_t)(by * 128 + s0 * 16 + lr) * K_DIM + lk;
    const unsigned short* a1 = A + (size_t)(by * 128 + s1 * 16 + lr) * K_DIM + lk;
    const unsigned short* b0 = B + (size_t)(bx * 128 + s0 * 16 + lr) * K_DIM + lk;
    const unsigned short* b1 = B + (size_t)(bx * 128 + s1 * 16 + lr) * K_DIM + lk;
    unsigned short* lA0 = &sA[s0 * 512];   // wave-uniform LDS bases
    unsigned short* lA1 = &sA[s1 * 512];
    unsigned short* lB0 = &sB[s0 * 512];
    unsigned short* lB1 = &sB[s1 * 512];

    const int wm   = (w >> 1) * 64;   // wave's 64x64 quadrant
    const int wn   = (w & 1) * 64;
    const int quad = l >> 4;
    const int l16  = l & 15;

    f32x4 acc[4][4] = {};

    for (int kt = 0; kt < 32; ++kt) {
        __syncthreads();                       // prior compute done with LDS
        GLOAD_LDS16(a0, lA0);
        GLOAD_LDS16(a1, lA1);
        GLOAD_LDS16(b0, lB0);
        GLOAD_LDS16(b1, lB1);
        a0 += 32; a1 += 32; b0 += 32; b1 += 32;
        __syncthreads();                       // staging visible

        bf16x8 af[4], bfr[4];
        #pragma unroll
        for (int i = 0; i < 4; ++i)
            af[i] = *(const bf16x8*)&sA[(wm + i * 16 + l16) * 32 + quad * 8];
        #pragma unroll
        for (int j = 0; j < 4; ++j)
            bfr[j] = *(const bf16x8*)&sB[(wn + j * 16 + l16) * 32 + quad * 8];

        #pragma unroll
        for (int i = 0; i < 4; ++i)
            #pragma unroll
            for (int j = 0; j < 4; ++j)
                acc[i][j] = __builtin_amdgcn_mfma_f32_16x16x32_bf16(
                    af[i], bfr[j], acc[i][j], 0, 0, 0);
    }

    // Epilogue. C/D layout: col = lane&15, row = quad*4 + reg (m89/m91 verified).
    const int row0 = by * 128 + wm + quad * 4;
    if (bx < 32) {
        const int  sec = bx >> 3;                       // 0:Q 1:K 2:V 3:gate
        const int  cb  = ((bx & 7) << 7) + wn + l16;    // col within 1024-wide section
        const bool isG = (sec == 3);
        float* o = out + (size_t)sec * SEC_ELEMS;
        #pragma unroll
        for (int i = 0; i < 4; ++i) {
            #pragma unroll
            for (int r = 0; r < 4; ++r) {
                const int row = row0 + i * 16 + r;
                const size_t base = (size_t)row * 1024 + cb;
                #pragma unroll
                for (int j = 0; j < 4; ++j) {
                    float v = acc[i][j][r];
                    if (isG) v = v / (1.f + __expf(-v));   // silu
                    o[base + j * 16] = v;
                }
            }
        }
    } else {
        // alpha tile: only cols 4096..4111 valid (wn==0, j==0, l16 0..15)
        if (wn == 0) {
            float* o = out + 4 * SEC_ELEMS;
            #pragma unroll
            for (int i = 0; i < 4; ++i) {
                #pragma unroll
                for (int r = 0; r < 4; ++r) {
                    const int row = row0 + i * 16 + r;
                    const float v = acc[i][0][r];
                    o[(size_t)row * 16 + l16] = 1.f / (1.f + __expf(-v));  // sigmoid
                }
            }
        }
    }
}

// ---- K row-normalization (in place on d_out) ----------------------------
__global__ void knorm_kernel(float* __restrict__ out) {
    const int m = blockIdx.x;                  // one block per row
    float* k = out + SEC_ELEMS + (size_t)m * 1024;
    float4 v = ((float4*)k)[threadIdx.x];
    float ss = v.x * v.x + v.y * v.y + v.z * v.z + v.w * v.w;
    #pragma unroll
    for (int off = 32; off > 0; off >>= 1)
        ss += __shfl_down(ss, off);            // width 64
    __shared__ float red[4];
    if ((threadIdx.x & 63) == 0) red[threadIdx.x >> 6] = ss;
    __syncthreads();
    const float tot = red[0] + red[1] + red[2] + red[3];
    const float scale = 1.f / fmaxf(sqrtf(tot), 1e-12f);
    v.x *= scale; v.y *= scale; v.z *= scale; v.w *= scale;
    ((float4*)k)[threadIdx.x] = v;
}

// ---- launch -------------------------------------------------------------
extern "C" void kernel_launch(void* const* d_in, const int* in_sizes, int n_in,
                              void* d_out, int out_size, void* d_ws, size_t ws_size,
                              hipStream_t stream) {
    const float* x = (const float*)d_in[0];   // (4,8192,1024) fp32
    const float* W = (const float*)d_in[1];   // (4112,1024)  fp32
    float* out = (float*)d_out;

    unsigned short* xb = (unsigned short*)d_ws;                 // 32768x1024 bf16 (64 MiB)
    unsigned short* Wb = xb + (size_t)M_ROWS * K_DIM;           // 4224x1024 bf16  (8.25 MiB)

    cvt_x_kernel<<<M_ROWS * K_DIM / 4 / 256, 256, 0, stream>>>(x, xb);
    cvt_w_kernel<<<N_PAD * K_DIM / 4 / 256, 256, 0, stream>>>(W, Wb);
    gemm_kernel<<<dim3(33, 256), 256, 0, stream>>>(xb, Wb, out);
    knorm_kernel<<<M_ROWS, 256, 0, stream>>>(out);
}